// Round 8
// baseline (317.663 us; speedup 1.0000x reference)
//
#include <hip/hip_runtime.h>

typedef unsigned short ushort;
typedef __attribute__((ext_vector_type(8))) short short8;
typedef __attribute__((ext_vector_type(4))) float f32x4;

#define NH 16
#define DH 128
#define SEQ 2048
#define DMODEL 2048
#define GK 2048   // K dim for both GEMMs
#define NT 32     // GK / 64

#define WAITVM(N) asm volatile("s_waitcnt vmcnt(" #N ")" ::: "memory")

__device__ __forceinline__ ushort f2bf(float f) {
  union { float f; unsigned u; } v; v.f = f;
  unsigned u = v.u;
  unsigned r = (u + 0x7fffu + ((u >> 16) & 1u)) >> 16;
  return (ushort)r;
}
__device__ __forceinline__ float bf2f(ushort h) {
  union { unsigned u; float f; } v; v.u = ((unsigned)h) << 16; return v.f;
}

__device__ __forceinline__ void async16(const ushort* g, ushort* l) {
  __builtin_amdgcn_global_load_lds(
      (const __attribute__((address_space(1))) unsigned*)g,
      (__attribute__((address_space(3))) unsigned*)l, 16, 0, 0);
}

// ---------------- cast fp32 -> bf16, 4 elems/thread ----------------
__global__ void cast_kernel(const float* __restrict__ src, ushort* __restrict__ dst, int n4) {
  int i = blockIdx.x * blockDim.x + threadIdx.x;
  if (i >= n4) return;
  float4 v = ((const float4*)src)[i];
  unsigned long long p = (unsigned long long)f2bf(v.x)
                       | ((unsigned long long)f2bf(v.y) << 16)
                       | ((unsigned long long)f2bf(v.z) << 32)
                       | ((unsigned long long)f2bf(v.w) << 48);
  ((unsigned long long*)dst)[i] = p;
}

// ---------------- 128x256 GEMM: C = A[M,K] * B[N,K]^T (bf16 MFMA) ----------------
// 512 threads = 8 waves (2M x 4N); wave tile 64x64 (4mf x 4nf frags).
// BK=64, XOR-swizzled LDS (pre-swizzled global_load_lds source + swizzled reads).
// Staging for tile t+1 spread across tile t: {A-half0(1 ld), A-half1(1), B01(2), B23(2)}.
// Counted vmcnt(1) once per tile (never drains); 2 barriers per tile.
// Race ledger: reads <- cur only; writes -> nxt only; tile-end barrier closes
// the (t+1 p0 stage into old-cur) vs (t p3 reads of old-cur) window.
__device__ __forceinline__ void stageA128(const ushort* Ablk, int k0, ushort* dst,
                                          int half, int tid) {
  int rl = tid >> 3, slot = tid & 7;
  int grow = half * 64 + rl;
  int col = ((slot * 16) ^ ((grow & 7) << 4)) >> 1;
  async16(Ablk + (size_t)grow * GK + k0 + col, dst + half * 4096 + tid * 8);
}
__device__ __forceinline__ void stageB256(const ushort* Bblk, int k0, ushort* dst,
                                          int pair, int tid) {
#pragma unroll
  for (int j = 0; j < 2; ++j) {
    int u = pair * 2 + j;                  // B unit = 64 rows
    int grow = u * 64 + (tid >> 3);
    int slot = tid & 7;
    int col = ((slot * 16) ^ ((grow & 7) << 4)) >> 1;
    async16(Bblk + (size_t)grow * GK + k0 + col, dst + u * 4096 + tid * 8);
  }
}

template<int MODE>
__global__ __launch_bounds__(512, 1)
void gemm128(const ushort* __restrict__ A, const ushort* __restrict__ B, int N,
             ushort* __restrict__ oq, ushort* __restrict__ ok, ushort* __restrict__ ov,
             float* __restrict__ of) {
  __shared__ ushort As[2][128 * 64];       // 32 KB
  __shared__ ushort Bs[2][256 * 64];       // 64 KB  (96 KB total)
  const int tid = threadIdx.x;
  const int lane = tid & 63;
  const int w = tid >> 6;
  const int wr = w >> 2, wc = w & 3;
  const int g = lane >> 4, l16 = lane & 15;
  const int m0 = blockIdx.y * 128;
  const int n0 = blockIdx.x * 256;
  const ushort* Ablk = A + (size_t)m0 * GK;
  const ushort* Bblk = B + (size_t)n0 * GK;

  f32x4 acc[4][4];
#pragma unroll
  for (int mf = 0; mf < 4; ++mf)
#pragma unroll
    for (int nf = 0; nf < 4; ++nf) acc[mf][nf] = (f32x4)0.f;

  // prologue: stage tile 0 into buffer 0 (6 loads/thread)
  stageA128(Ablk, 0, As[0], 0, tid);
  stageA128(Ablk, 0, As[0], 1, tid);
  stageB256(Bblk, 0, Bs[0], 0, tid);
  stageB256(Bblk, 0, Bs[0], 1, tid);

  for (int t = 0; t < NT; ++t) {
    const int kn = (t + 1) * 64;
    const bool pre = (t + 1 < NT);
    const ushort* curA = As[t & 1];
    const ushort* curB = Bs[t & 1];
    ushort* nxtA = (ushort*)As[(t & 1) ^ 1];
    ushort* nxtB = (ushort*)Bs[(t & 1) ^ 1];

    // ---- phase 0: stage A0(t+1), counted wait, barrier ----
    if (pre) { stageA128(Ablk, kn, nxtA, 0, tid); WAITVM(1); }
    else     { WAITVM(0); }
    __builtin_amdgcn_sched_barrier(0);
    __builtin_amdgcn_s_barrier();
    __builtin_amdgcn_sched_barrier(0);

    // B-frags for the whole tile (8 x b128), hoisted
    short8 bfr[4][2];
#pragma unroll
    for (int nf = 0; nf < 4; ++nf)
#pragma unroll
      for (int ks = 0; ks < 2; ++ks) {
        int row = wc * 64 + nf * 16 + l16;
        bfr[nf][ks] = *(const short8*)&curB[row * 64 + (((ks * 64 + g * 16) ^ ((l16 & 7) << 4)) >> 1)];
      }

    // ---- 4 compute phases: mf = p; stage one unit between phases ----
#pragma unroll
    for (int p = 0; p < 4; ++p) {
      if (pre) {
        if (p == 1)      stageA128(Ablk, kn, nxtA, 1, tid);
        else if (p == 2) stageB256(Bblk, kn, nxtB, 0, tid);
        else if (p == 3) stageB256(Bblk, kn, nxtB, 1, tid);
      }
      short8 af[2];
      int row = wr * 64 + p * 16 + l16;
#pragma unroll
      for (int ks = 0; ks < 2; ++ks)
        af[ks] = *(const short8*)&curA[row * 64 + (((ks * 64 + g * 16) ^ ((l16 & 7) << 4)) >> 1)];
      __builtin_amdgcn_s_setprio(1);
#pragma unroll
      for (int nf = 0; nf < 4; ++nf)
#pragma unroll
        for (int ks = 0; ks < 2; ++ks)
          acc[p][nf] = __builtin_amdgcn_mfma_f32_16x16x32_bf16(af[ks], bfr[nf][ks], acc[p][nf], 0, 0, 0);
      __builtin_amdgcn_s_setprio(0);
    }

    __builtin_amdgcn_sched_barrier(0);
    __builtin_amdgcn_s_barrier();
    __builtin_amdgcn_sched_barrier(0);
  }

#pragma unroll
  for (int mf = 0; mf < 4; ++mf)
#pragma unroll
    for (int nf = 0; nf < 4; ++nf)
#pragma unroll
      for (int i = 0; i < 4; ++i) {
        int row = m0 + wr * 64 + mf * 16 + g * 4 + i;
        int col = n0 + wc * 64 + nf * 16 + l16;
        float val = acc[mf][nf][i];
        if (MODE == 0) {
          int which = col >> 11;
          int r = col & 2047;
          int h = r >> 7, dh = r & 127;
          int b = row >> 11, s = row & 2047;
          size_t dst = ((size_t)(b * NH + h) * SEQ + s) * DH + dh;
          ushort* o = (which == 0) ? oq : (which == 1 ? ok : ov);
          o[dst] = f2bf(val);
        } else {
          of[(size_t)row * N + col] = val;
        }
      }
}

// ---------------- RoPE (in-place on head-major bf16 q,k) ----------------
__global__ void rope_kernel(ushort* __restrict__ q, ushort* __restrict__ k,
                            const int* __restrict__ spp) {
  int id = blockIdx.x * blockDim.x + threadIdx.x;   // < B*H*S*64
  int j = id & 63;
  int s = (id >> 6) & (SEQ - 1);
  int bh = id >> 17;
  size_t base = ((size_t)bh * SEQ + s) * DH;
  float pos = (float)(s + spp[0]);
  float ang = pos * __expf(-(float)j * (9.210340371976184f / 64.f)); // 1/10000^(j/64)
  float c = cosf(ang), sn = sinf(ang);
  float q1 = bf2f(q[base + j]), q2 = bf2f(q[base + 64 + j]);
  q[base + j]      = f2bf(q1 * c - q2 * sn);
  q[base + 64 + j] = f2bf(q2 * c + q1 * sn);
  float k1 = bf2f(k[base + j]), k2 = bf2f(k[base + 64 + j]);
  k[base + j]      = f2bf(k1 * c - k2 * sn);
  k[base + 64 + j] = f2bf(k2 * c + k1 * sn);
}

// ---------------- causal flash attention ----------------
// grid: (16, H, B) = 512 blocks; block bx processes q-tile (31-bx) then q-tile
// bx SEQUENTIALLY -> every block does exactly 33 KV-tiles (uniform load).
// 256 threads = 4 waves; wave w owns 16 q-rows. QBLK=64, KBLK=64.
// Double-buffered K (XOR-swizzled, pre-swizzled source) and Vt (transposed,
// stride 72, XOR kv-swizzle). One barrier per tile (stage t+1 before compute t).
__global__ __launch_bounds__(256, 2)
void attn_kernel(const ushort* __restrict__ Q, const ushort* __restrict__ K,
                 const ushort* __restrict__ V, ushort* __restrict__ O) {
  __shared__ ushort Ks[2][64 * 128];     // 32 KB
  __shared__ ushort Vt[2][128 * 72];     // 36 KB
  __shared__ ushort Ps[4][16 * 72];      // 9 KB
  const int tid = threadIdx.x;
  const int lane = tid & 63;
  const int w = tid >> 6;
  const int g = lane >> 4, l16 = lane & 15;
  const int h = blockIdx.y, b = blockIdx.z;
  const int bh = b * NH + h;
  const ushort* Qb = Q + (size_t)bh * SEQ * DH;
  const ushort* Kb = K + (size_t)bh * SEQ * DH;
  const ushort* Vb = V + (size_t)bh * SEQ * DH;
  const float scale = 0.08838834764831845f;  // 1/sqrt(128)

  // V staging decode: thread covers kv rows {vkv, vkv+1} x cols [vd0, vd0+16)
  const int vkv = (tid >> 3) * 2;       // 0..62
  const int vd0 = (tid & 7) * 16;       // 0..112
  const int vmask = (tid & 7) << 3;     // XOR swizzle ((d>>4)&7)<<3

  for (int pass = 0; pass < 2; ++pass) {
    const int qt = pass == 0 ? (31 - (int)blockIdx.x) : (int)blockIdx.x;
    const int q0 = qt * 64;
    const int nkt = qt + 1;

    short8 qf[4];
    {
      const ushort* qrow = Qb + (size_t)(q0 + w * 16 + l16) * DH;
#pragma unroll
      for (int ks = 0; ks < 4; ++ks) qf[ks] = *(const short8*)(qrow + ks * 32 + g * 8);
    }
    f32x4 oacc[8];
#pragma unroll
    for (int i = 0; i < 8; ++i) oacc[i] = (f32x4)0.f;
    float m_i[4], l_i[4];
#pragma unroll
    for (int i = 0; i < 4; ++i) { m_i[i] = -INFINITY; l_i[i] = 0.f; }

    // ---- prologue: stage tile 0 into buffer 0 ----
#pragma unroll
    for (int it = 0; it < 4; ++it) {
      int ci = it * 256 + tid;
      int row = ci >> 4;
      int cb = ((ci & 15) * 16) ^ ((row & 7) << 4);
      async16(Kb + (size_t)row * DH + (cb >> 1), &Ks[0][ci * 8]);
    }
    {
      short8 vr[4];
      vr[0] = *(const short8*)(Vb + (size_t)vkv * DH + vd0);
      vr[1] = *(const short8*)(Vb + (size_t)vkv * DH + vd0 + 8);
      vr[2] = *(const short8*)(Vb + (size_t)(vkv + 1) * DH + vd0);
      vr[3] = *(const short8*)(Vb + (size_t)(vkv + 1) * DH + vd0 + 8);
#pragma unroll
      for (int j = 0; j < 16; ++j) {
        int d = vd0 + j;
        const ushort* a = (const ushort*)&vr[j >> 3];
        const ushort* c = (const ushort*)&vr[2 + (j >> 3)];
        unsigned val = (unsigned)a[j & 7] | ((unsigned)c[j & 7] << 16);
        *(unsigned*)&Vt[0][d * 72 + (vkv ^ vmask)] = val;
      }
    }
    __syncthreads();

    int cur = 0;
    for (int t = 0; t < nkt; ++t) {
      const int k0 = t * 64;
      const int nxt = cur ^ 1;
      const bool pre = (t + 1 < nkt);
      short8 vr[4];
      if (pre) {
        const int kn = (t + 1) * 64;
#pragma unroll
        for (int it = 0; it < 4; ++it) {
          int ci = it * 256 + tid;
          int row = ci >> 4;
          int cb = ((ci & 15) * 16) ^ ((row & 7) << 4);
          async16(Kb + (size_t)(kn + row) * DH + (cb >> 1), &Ks[nxt][ci * 8]);
        }
        vr[0] = *(const short8*)(Vb + (size_t)(kn + vkv) * DH + vd0);
        vr[1] = *(const short8*)(Vb + (size_t)(kn + vkv) * DH + vd0 + 8);
        vr[2] = *(const short8*)(Vb + (size_t)(kn + vkv + 1) * DH + vd0);
        vr[3] = *(const short8*)(Vb + (size_t)(kn + vkv + 1) * DH + vd0 + 8);
      }

      // ---- QK^T : S[16 q][64 keys] per wave ----
      f32x4 sacc[4];
#pragma unroll
      for (int nf = 0; nf < 4; ++nf) sacc[nf] = (f32x4)0.f;
      __builtin_amdgcn_s_setprio(1);
#pragma unroll
      for (int nf = 0; nf < 4; ++nf) {
        int row = nf * 16 + l16;
#pragma unroll
        for (int ks = 0; ks < 4; ++ks) {
          int cb = (ks * 64 + g * 16) ^ ((l16 & 7) << 4);
          short8 kf = *(const short8*)&Ks[cur][row * 128 + (cb >> 1)];
          sacc[nf] = __builtin_amdgcn_mfma_f32_16x16x32_bf16(qf[ks], kf, sacc[nf], 0, 0, 0);
        }
      }
      __builtin_amdgcn_s_setprio(0);

      // ---- online softmax ----
#pragma unroll
      for (int i = 0; i < 4; ++i) {
        int qrow = q0 + w * 16 + g * 4 + i;
        float pv[4];
#pragma unroll
        for (int nf = 0; nf < 4; ++nf) {
          pv[nf] = sacc[nf][i] * scale;
          if (k0 + nf * 16 + l16 > qrow) pv[nf] = -INFINITY;
        }
        float mx = fmaxf(fmaxf(pv[0], pv[1]), fmaxf(pv[2], pv[3]));
#pragma unroll
        for (int d = 1; d < 16; d <<= 1) mx = fmaxf(mx, __shfl_xor(mx, d, 64));
        float mnew = fmaxf(m_i[i], mx);
        float alpha = __expf(m_i[i] - mnew);
        float p[4], sum = 0.f;
#pragma unroll
        for (int nf = 0; nf < 4; ++nf) { p[nf] = __expf(pv[nf] - mnew); sum += p[nf]; }
#pragma unroll
        for (int d = 1; d < 16; d <<= 1) sum += __shfl_xor(sum, d, 64);
        l_i[i] = l_i[i] * alpha + sum;
        m_i[i] = mnew;
#pragma unroll
        for (int nf2 = 0; nf2 < 8; ++nf2) oacc[nf2][i] *= alpha;
#pragma unroll
        for (int nf = 0; nf < 4; ++nf)
          Ps[w][(g * 4 + i) * 72 + nf * 16 + l16] = f2bf(p[nf]);
      }
      __asm__ volatile("s_waitcnt lgkmcnt(0)" ::: "memory");
      __builtin_amdgcn_sched_barrier(0);

      // ---- PV: O[16 q][128 dh] += P[16][64] @ V[64][128] ----
      __builtin_amdgcn_s_setprio(1);
#pragma unroll
      for (int kvh = 0; kvh < 2; ++kvh) {
        short8 pa = *(const short8*)&Ps[w][l16 * 72 + kvh * 32 + g * 8];
#pragma unroll
        for (int nf2 = 0; nf2 < 8; ++nf2) {
          int cb = (kvh * 32 + g * 8) ^ (nf2 * 8);
          short8 vf = *(const short8*)&Vt[cur][(nf2 * 16 + l16) * 72 + cb];
          oacc[nf2] = __builtin_amdgcn_mfma_f32_16x16x32_bf16(pa, vf, oacc[nf2], 0, 0, 0);
        }
      }
      __builtin_amdgcn_s_setprio(0);

      if (pre) {
#pragma unroll
        for (int j = 0; j < 16; ++j) {
          int d = vd0 + j;
          const ushort* a = (const ushort*)&vr[j >> 3];
          const ushort* c = (const ushort*)&vr[2 + (j >> 3)];
          unsigned val = (unsigned)a[j & 7] | ((unsigned)c[j & 7] << 16);
          *(unsigned*)&Vt[nxt][d * 72 + (vkv ^ vmask)] = val;
        }
      }
      __syncthreads();
      cur = nxt;
    }

    // ---- epilogue: write O rows for this pass ----
#pragma unroll
    for (int i = 0; i < 4; ++i) {
      float inv = 1.f / l_i[i];
      int row = q0 + w * 16 + g * 4 + i;
      size_t obase = ((size_t)b * SEQ + row) * DMODEL + h * DH;
#pragma unroll
      for (int nf2 = 0; nf2 < 8; ++nf2)
        O[obase + nf2 * 16 + l16] = f2bf(oacc[nf2][i] * inv);
    }
  }
}

// ---------------- launch ----------------
extern "C" void kernel_launch(void* const* d_in, const int* in_sizes, int n_in,
                              void* d_out, int out_size, void* d_ws, size_t ws_size,
                              hipStream_t stream) {
  const float* x    = (const float*)d_in[0];
  const float* wqkv = (const float*)d_in[1];
  const float* wout = (const float*)d_in[2];
  const int*   spp  = (const int*)d_in[3];
  float* out = (float*)d_out;

  ushort* ws = (ushort*)d_ws;
  ushort* xb  = ws;                       // 8,388,608
  ushort* wqb = xb + 8388608;             // 12,582,912
  ushort* wob = wqb + 12582912;           // 4,194,304
  ushort* q   = wob + 4194304;            // 8,388,608
  ushort* k   = q + 8388608;
  ushort* v   = k + 8388608;
  ushort* ao  = v + 8388608;              // 8,388,608

  cast_kernel<<<8388608 / 1024, 256, 0, stream>>>(x, xb, 8388608 / 4);
  cast_kernel<<<12582912 / 1024, 256, 0, stream>>>(wqkv, wqb, 12582912 / 4);
  cast_kernel<<<4194304 / 1024, 256, 0, stream>>>(wout, wob, 4194304 / 4);

  gemm128<0><<<dim3(6144 / 256, 4096 / 128), 512, 0, stream>>>(xb, wqb, 6144, q, k, v, nullptr);

  rope_kernel<<<4194304 / 256, 256, 0, stream>>>(q, k, spp);

  attn_kernel<<<dim3(16, NH, 2), 256, 0, stream>>>(q, k, v, ao);

  gemm128<1><<<dim3(2048 / 256, 4096 / 128), 512, 0, stream>>>(ao, wob, 2048, nullptr, nullptr, nullptr, out);
}

// Round 9
// 293.540 us; speedup vs baseline: 1.0822x; 1.0822x over previous
//
#include <hip/hip_runtime.h>

typedef unsigned short ushort;
typedef __attribute__((ext_vector_type(8))) short short8;
typedef __attribute__((ext_vector_type(4))) float f32x4;

#define NH 16
#define DH 128
#define SEQ 2048
#define DMODEL 2048
#define GK 2048   // K dim for both GEMMs
#define NT 32     // GK / 64

#define WAITVM(N) asm volatile("s_waitcnt vmcnt(" #N ")" ::: "memory")

__device__ __forceinline__ ushort f2bf(float f) {
  union { float f; unsigned u; } v; v.f = f;
  unsigned u = v.u;
  unsigned r = (u + 0x7fffu + ((u >> 16) & 1u)) >> 16;
  return (ushort)r;
}
__device__ __forceinline__ float bf2f(ushort h) {
  union { unsigned u; float f; } v; v.u = ((unsigned)h) << 16; return v.f;
}

__device__ __forceinline__ void async16(const ushort* g, ushort* l) {
  __builtin_amdgcn_global_load_lds(
      (const __attribute__((address_space(1))) unsigned*)g,
      (__attribute__((address_space(3))) unsigned*)l, 16, 0, 0);
}

// ---------------- cast fp32 -> bf16, 4 elems/thread ----------------
__global__ void cast_kernel(const float* __restrict__ src, ushort* __restrict__ dst, int n4) {
  int i = blockIdx.x * blockDim.x + threadIdx.x;
  if (i >= n4) return;
  float4 v = ((const float4*)src)[i];
  unsigned long long p = (unsigned long long)f2bf(v.x)
                       | ((unsigned long long)f2bf(v.y) << 16)
                       | ((unsigned long long)f2bf(v.z) << 32)
                       | ((unsigned long long)f2bf(v.w) << 48);
  ((unsigned long long*)dst)[i] = p;
}

// ---------------- 128x256 GEMM, TRIPLE-buffered, 2-tile-ahead prefetch ----
// C = A[M,K] * B[N,K]^T.  512 threads = 8 waves (2Mx4N), wave tile 64x64.
// BK=64.  LDS: 3 bufs x (A 16KB + B 32KB) = 144 KB.  XOR-swizzled
// (pre-swizzled global source + swizzled ds_read_b128; involution verified).
// Stage plan per tile t (for tile t+2, 6 loads/thread): A(2)@p0, B(2)@mid,
// B(2)@end.  Counted waits (ledger): steady vmcnt(8) = t+1's 6 + t+2's A 2;
// t=NT-2 -> 6; t=NT-1 -> 0.  Loads never drained in main loop.
// Races: stage->buf((t+2)%3) = buffer last READ by tile t-1, whose reads end
// at t-1's end barrier (before these issues).  Tile-t reads covered by the
// p0 wait + barrier (collective).  2 barriers/tile.
__device__ __forceinline__ void stageA6(const ushort* Ablk, int k0, ushort* dst, int tid) {
#pragma unroll
  for (int j = 0; j < 2; ++j) {
    int c = j * 512 + tid;                 // 1024 chunks of 16B (128 rows)
    int rl = c >> 3, sl = c & 7;
    int col = ((sl * 16) ^ ((rl & 7) << 4)) >> 1;
    async16(Ablk + (size_t)rl * GK + k0 + col, dst + c * 8);
  }
}
__device__ __forceinline__ void stageB6(const ushort* Bblk, int k0, ushort* dst, int pair, int tid) {
#pragma unroll
  for (int j = 0; j < 2; ++j) {
    int c = (pair * 2 + j) * 512 + tid;    // 2048 chunks (256 rows)
    int rl = c >> 3, sl = c & 7;
    int col = ((sl * 16) ^ ((rl & 7) << 4)) >> 1;
    async16(Bblk + (size_t)rl * GK + k0 + col, dst + c * 8);
  }
}

template<int MODE>
__global__ __launch_bounds__(512, 1)
void gemm128(const ushort* __restrict__ A, const ushort* __restrict__ B, int N,
             ushort* __restrict__ oq, ushort* __restrict__ ok, ushort* __restrict__ ov,
             float* __restrict__ of) {
  __shared__ ushort As[3][128 * 64];       // 48 KB
  __shared__ ushort Bs[3][256 * 64];       // 96 KB
  const int tid = threadIdx.x;
  const int lane = tid & 63;
  const int w = tid >> 6;
  const int wr = w >> 2, wc = w & 3;       // 2 x 4 waves, 64x64 tile each
  const int g = lane >> 4, l16 = lane & 15;
  const int m0 = blockIdx.y * 128;
  const int n0 = blockIdx.x * 256;
  const ushort* Ablk = A + (size_t)m0 * GK;
  const ushort* Bblk = B + (size_t)n0 * GK;

  f32x4 acc[4][4];
#pragma unroll
  for (int mf = 0; mf < 4; ++mf)
#pragma unroll
    for (int nf = 0; nf < 4; ++nf) acc[mf][nf] = (f32x4)0.f;

  // prologue: stage tiles 0 and 1 (order A, Ba, Bb each -> ledger holds)
  stageA6(Ablk, 0, (ushort*)As[0], tid);
  stageB6(Bblk, 0, (ushort*)Bs[0], 0, tid);
  stageB6(Bblk, 0, (ushort*)Bs[0], 1, tid);
  stageA6(Ablk, 64, (ushort*)As[1], tid);
  stageB6(Bblk, 64, (ushort*)Bs[1], 0, tid);
  stageB6(Bblk, 64, (ushort*)Bs[1], 1, tid);

  const ushort* cA = As[0]; const ushort* cB = Bs[0];
  const ushort* nA = As[1]; const ushort* nB = Bs[1];
  ushort* pA = (ushort*)As[2]; ushort* pB = (ushort*)Bs[2];

  for (int t = 0; t < NT; ++t) {
    const int k2 = (t + 2) * 64;
    const bool pre2 = (t + 2 < NT);

    if (pre2) stageA6(Ablk, k2, pA, tid);
    __builtin_amdgcn_sched_barrier(0);
    if (pre2)             { WAITVM(8); }
    else if (t + 1 < NT)  { WAITVM(6); }
    else                  { WAITVM(0); }
    __builtin_amdgcn_sched_barrier(0);
    __builtin_amdgcn_s_barrier();
    __builtin_amdgcn_sched_barrier(0);

    // ---- phase 0: A-frags (8 reads) + B-half0 (4 reads), 16 MFMA ----
    short8 af[4][2], bf[2][2];
#pragma unroll
    for (int mf = 0; mf < 4; ++mf) {
      int row = wr * 64 + mf * 16 + l16;
#pragma unroll
      for (int ks = 0; ks < 2; ++ks)
        af[mf][ks] = *(const short8*)&cA[row * 64 + (((ks * 64 + g * 16) ^ ((l16 & 7) << 4)) >> 1)];
    }
#pragma unroll
    for (int nf = 0; nf < 2; ++nf) {
      int row = wc * 64 + nf * 16 + l16;
#pragma unroll
      for (int ks = 0; ks < 2; ++ks)
        bf[nf][ks] = *(const short8*)&cB[row * 64 + (((ks * 64 + g * 16) ^ ((l16 & 7) << 4)) >> 1)];
    }
    __builtin_amdgcn_s_setprio(1);
#pragma unroll
    for (int mf = 0; mf < 4; ++mf)
#pragma unroll
      for (int nf = 0; nf < 2; ++nf)
#pragma unroll
        for (int ks = 0; ks < 2; ++ks)
          acc[mf][nf] = __builtin_amdgcn_mfma_f32_16x16x32_bf16(af[mf][ks], bf[nf][ks], acc[mf][nf], 0, 0, 0);
    __builtin_amdgcn_s_setprio(0);

    if (pre2) stageB6(Bblk, k2, pB, 0, tid);

    // ---- phase 1: B-half1 (4 reads), 16 MFMA ----
#pragma unroll
    for (int nf = 0; nf < 2; ++nf) {
      int row = wc * 64 + 32 + nf * 16 + l16;
#pragma unroll
      for (int ks = 0; ks < 2; ++ks)
        bf[nf][ks] = *(const short8*)&cB[row * 64 + (((ks * 64 + g * 16) ^ ((l16 & 7) << 4)) >> 1)];
    }
    __builtin_amdgcn_s_setprio(1);
#pragma unroll
    for (int mf = 0; mf < 4; ++mf)
#pragma unroll
      for (int nf = 0; nf < 2; ++nf)
#pragma unroll
        for (int ks = 0; ks < 2; ++ks)
          acc[mf][2 + nf] = __builtin_amdgcn_mfma_f32_16x16x32_bf16(af[mf][ks], bf[nf][ks], acc[mf][2 + nf], 0, 0, 0);
    __builtin_amdgcn_s_setprio(0);

    if (pre2) stageB6(Bblk, k2, pB, 1, tid);
    __builtin_amdgcn_sched_barrier(0);
    __builtin_amdgcn_s_barrier();
    __builtin_amdgcn_sched_barrier(0);

    // rotate buffers: (c, n, p) <- (n, p, c)
    const ushort* tA = cA; const ushort* tB = cB;
    cA = nA; cB = nB;
    nA = pA; nB = pB;
    pA = (ushort*)tA; pB = (ushort*)tB;
  }

#pragma unroll
  for (int mf = 0; mf < 4; ++mf)
#pragma unroll
    for (int nf = 0; nf < 4; ++nf)
#pragma unroll
      for (int i = 0; i < 4; ++i) {
        int row = m0 + wr * 64 + mf * 16 + g * 4 + i;
        int col = n0 + wc * 64 + nf * 16 + l16;
        float val = acc[mf][nf][i];
        if (MODE == 0) {
          int which = col >> 11;
          int r = col & 2047;
          int h = r >> 7, dh = r & 127;
          int b = row >> 11, s = row & 2047;
          size_t dst = ((size_t)(b * NH + h) * SEQ + s) * DH + dh;
          ushort* o = (which == 0) ? oq : (which == 1 ? ok : ov);
          o[dst] = f2bf(val);
        } else {
          of[(size_t)row * N + col] = val;
        }
      }
}

// ---------------- RoPE (in-place on head-major bf16 q,k) ----------------
__global__ void rope_kernel(ushort* __restrict__ q, ushort* __restrict__ k,
                            const int* __restrict__ spp) {
  int id = blockIdx.x * blockDim.x + threadIdx.x;   // < B*H*S*64
  int j = id & 63;
  int s = (id >> 6) & (SEQ - 1);
  int bh = id >> 17;
  size_t base = ((size_t)bh * SEQ + s) * DH;
  float pos = (float)(s + spp[0]);
  float ang = pos * __expf(-(float)j * (9.210340371976184f / 64.f)); // 1/10000^(j/64)
  float c = cosf(ang), sn = sinf(ang);
  float q1 = bf2f(q[base + j]), q2 = bf2f(q[base + 64 + j]);
  q[base + j]      = f2bf(q1 * c - q2 * sn);
  q[base + 64 + j] = f2bf(q2 * c + q1 * sn);
  float k1 = bf2f(k[base + j]), k2 = bf2f(k[base + 64 + j]);
  k[base + j]      = f2bf(k1 * c - k2 * sn);
  k[base + 64 + j] = f2bf(k2 * c + k1 * sn);
}

// ---------------- causal flash attention (unchanged, passing) ----------------
__global__ __launch_bounds__(256, 2)
void attn_kernel(const ushort* __restrict__ Q, const ushort* __restrict__ K,
                 const ushort* __restrict__ V, ushort* __restrict__ O) {
  __shared__ ushort Ks[2][64 * 128];     // 32 KB
  __shared__ ushort Vt[2][128 * 72];     // 36 KB
  __shared__ ushort Ps[4][16 * 72];      // 9 KB
  const int tid = threadIdx.x;
  const int lane = tid & 63;
  const int w = tid >> 6;
  const int g = lane >> 4, l16 = lane & 15;
  const int h = blockIdx.y, b = blockIdx.z;
  const int bh = b * NH + h;
  const ushort* Qb = Q + (size_t)bh * SEQ * DH;
  const ushort* Kb = K + (size_t)bh * SEQ * DH;
  const ushort* Vb = V + (size_t)bh * SEQ * DH;
  const float scale = 0.08838834764831845f;  // 1/sqrt(128)

  const int vkv = (tid >> 3) * 2;       // 0..62
  const int vd0 = (tid & 7) * 16;       // 0..112
  const int vmask = (tid & 7) << 3;     // XOR swizzle ((d>>4)&7)<<3

  for (int pass = 0; pass < 2; ++pass) {
    const int qt = pass == 0 ? (31 - (int)blockIdx.x) : (int)blockIdx.x;
    const int q0 = qt * 64;
    const int nkt = qt + 1;

    short8 qf[4];
    {
      const ushort* qrow = Qb + (size_t)(q0 + w * 16 + l16) * DH;
#pragma unroll
      for (int ks = 0; ks < 4; ++ks) qf[ks] = *(const short8*)(qrow + ks * 32 + g * 8);
    }
    f32x4 oacc[8];
#pragma unroll
    for (int i = 0; i < 8; ++i) oacc[i] = (f32x4)0.f;
    float m_i[4], l_i[4];
#pragma unroll
    for (int i = 0; i < 4; ++i) { m_i[i] = -INFINITY; l_i[i] = 0.f; }

#pragma unroll
    for (int it = 0; it < 4; ++it) {
      int ci = it * 256 + tid;
      int row = ci >> 4;
      int cb = ((ci & 15) * 16) ^ ((row & 7) << 4);
      async16(Kb + (size_t)row * DH + (cb >> 1), &Ks[0][ci * 8]);
    }
    {
      short8 vr[4];
      vr[0] = *(const short8*)(Vb + (size_t)vkv * DH + vd0);
      vr[1] = *(const short8*)(Vb + (size_t)vkv * DH + vd0 + 8);
      vr[2] = *(const short8*)(Vb + (size_t)(vkv + 1) * DH + vd0);
      vr[3] = *(const short8*)(Vb + (size_t)(vkv + 1) * DH + vd0 + 8);
#pragma unroll
      for (int j = 0; j < 16; ++j) {
        int d = vd0 + j;
        const ushort* a = (const ushort*)&vr[j >> 3];
        const ushort* c = (const ushort*)&vr[2 + (j >> 3)];
        unsigned val = (unsigned)a[j & 7] | ((unsigned)c[j & 7] << 16);
        *(unsigned*)&Vt[0][d * 72 + (vkv ^ vmask)] = val;
      }
    }
    __syncthreads();

    int cur = 0;
    for (int t = 0; t < nkt; ++t) {
      const int k0 = t * 64;
      const int nxt = cur ^ 1;
      const bool pre = (t + 1 < nkt);
      short8 vr[4];
      if (pre) {
        const int kn = (t + 1) * 64;
#pragma unroll
        for (int it = 0; it < 4; ++it) {
          int ci = it * 256 + tid;
          int row = ci >> 4;
          int cb = ((ci & 15) * 16) ^ ((row & 7) << 4);
          async16(Kb + (size_t)(kn + row) * DH + (cb >> 1), &Ks[nxt][ci * 8]);
        }
        vr[0] = *(const short8*)(Vb + (size_t)(kn + vkv) * DH + vd0);
        vr[1] = *(const short8*)(Vb + (size_t)(kn + vkv) * DH + vd0 + 8);
        vr[2] = *(const short8*)(Vb + (size_t)(kn + vkv + 1) * DH + vd0);
        vr[3] = *(const short8*)(Vb + (size_t)(kn + vkv + 1) * DH + vd0 + 8);
      }

      f32x4 sacc[4];
#pragma unroll
      for (int nf = 0; nf < 4; ++nf) sacc[nf] = (f32x4)0.f;
      __builtin_amdgcn_s_setprio(1);
#pragma unroll
      for (int nf = 0; nf < 4; ++nf) {
        int row = nf * 16 + l16;
#pragma unroll
        for (int ks = 0; ks < 4; ++ks) {
          int cb = (ks * 64 + g * 16) ^ ((l16 & 7) << 4);
          short8 kf = *(const short8*)&Ks[cur][row * 128 + (cb >> 1)];
          sacc[nf] = __builtin_amdgcn_mfma_f32_16x16x32_bf16(qf[ks], kf, sacc[nf], 0, 0, 0);
        }
      }
      __builtin_amdgcn_s_setprio(0);

#pragma unroll
      for (int i = 0; i < 4; ++i) {
        int qrow = q0 + w * 16 + g * 4 + i;
        float pv[4];
#pragma unroll
        for (int nf = 0; nf < 4; ++nf) {
          pv[nf] = sacc[nf][i] * scale;
          if (k0 + nf * 16 + l16 > qrow) pv[nf] = -INFINITY;
        }
        float mx = fmaxf(fmaxf(pv[0], pv[1]), fmaxf(pv[2], pv[3]));
#pragma unroll
        for (int d = 1; d < 16; d <<= 1) mx = fmaxf(mx, __shfl_xor(mx, d, 64));
        float mnew = fmaxf(m_i[i], mx);
        float alpha = __expf(m_i[i] - mnew);
        float p[4], sum = 0.f;
#pragma unroll
        for (int nf = 0; nf < 4; ++nf) { p[nf] = __expf(pv[nf] - mnew); sum += p[nf]; }
#pragma unroll
        for (int d = 1; d < 16; d <<= 1) sum += __shfl_xor(sum, d, 64);
        l_i[i] = l_i[i] * alpha + sum;
        m_i[i] = mnew;
#pragma unroll
        for (int nf2 = 0; nf2 < 8; ++nf2) oacc[nf2][i] *= alpha;
#pragma unroll
        for (int nf = 0; nf < 4; ++nf)
          Ps[w][(g * 4 + i) * 72 + nf * 16 + l16] = f2bf(p[nf]);
      }
      __asm__ volatile("s_waitcnt lgkmcnt(0)" ::: "memory");
      __builtin_amdgcn_sched_barrier(0);

      __builtin_amdgcn_s_setprio(1);
#pragma unroll
      for (int kvh = 0; kvh < 2; ++kvh) {
        short8 pa = *(const short8*)&Ps[w][l16 * 72 + kvh * 32 + g * 8];
#pragma unroll
        for (int nf2 = 0; nf2 < 8; ++nf2) {
          int cb = (kvh * 32 + g * 8) ^ (nf2 * 8);
          short8 vf = *(const short8*)&Vt[cur][(nf2 * 16 + l16) * 72 + cb];
          oacc[nf2] = __builtin_amdgcn_mfma_f32_16x16x32_bf16(pa, vf, oacc[nf2], 0, 0, 0);
        }
      }
      __builtin_amdgcn_s_setprio(0);

      if (pre) {
#pragma unroll
        for (int j = 0; j < 16; ++j) {
          int d = vd0 + j;
          const ushort* a = (const ushort*)&vr[j >> 3];
          const ushort* c = (const ushort*)&vr[2 + (j >> 3)];
          unsigned val = (unsigned)a[j & 7] | ((unsigned)c[j & 7] << 16);
          *(unsigned*)&Vt[nxt][d * 72 + (vkv ^ vmask)] = val;
        }
      }
      __syncthreads();
      cur = nxt;
    }

#pragma unroll
    for (int i = 0; i < 4; ++i) {
      float inv = 1.f / l_i[i];
      int row = q0 + w * 16 + g * 4 + i;
      size_t obase = ((size_t)b * SEQ + row) * DMODEL + h * DH;
#pragma unroll
      for (int nf2 = 0; nf2 < 8; ++nf2)
        O[obase + nf2 * 16 + l16] = f2bf(oacc[nf2][i] * inv);
    }
  }
}

// ---------------- launch ----------------
extern "C" void kernel_launch(void* const* d_in, const int* in_sizes, int n_in,
                              void* d_out, int out_size, void* d_ws, size_t ws_size,
                              hipStream_t stream) {
  const float* x    = (const float*)d_in[0];
  const float* wqkv = (const float*)d_in[1];
  const float* wout = (const float*)d_in[2];
  const int*   spp  = (const int*)d_in[3];
  float* out = (float*)d_out;

  ushort* ws = (ushort*)d_ws;
  ushort* xb  = ws;                       // 8,388,608
  ushort* wqb = xb + 8388608;             // 12,582,912
  ushort* wob = wqb + 12582912;           // 4,194,304
  ushort* q   = wob + 4194304;            // 8,388,608
  ushort* k   = q + 8388608;
  ushort* v   = k + 8388608;
  ushort* ao  = v + 8388608;              // 8,388,608

  cast_kernel<<<8388608 / 1024, 256, 0, stream>>>(x, xb, 8388608 / 4);
  cast_kernel<<<12582912 / 1024, 256, 0, stream>>>(wqkv, wqb, 12582912 / 4);
  cast_kernel<<<4194304 / 1024, 256, 0, stream>>>(wout, wob, 4194304 / 4);

  gemm128<0><<<dim3(6144 / 256, 4096 / 128), 512, 0, stream>>>(xb, wqb, 6144, q, k, v, nullptr);

  rope_kernel<<<4194304 / 256, 256, 0, stream>>>(q, k, spp);

  attn_kernel<<<dim3(16, NH, 2), 256, 0, stream>>>(q, k, v, ao);

  gemm128<1><<<dim3(2048 / 256, 4096 / 128), 512, 0, stream>>>(ao, wob, 2048, nullptr, nullptr, nullptr, out);
}